// Round 11
// baseline (252.408 us; speedup 1.0000x reference)
//
#include <hip/hip_runtime.h>
#include <stdint.h>

typedef unsigned short u16;
typedef unsigned int u32;
typedef u16 u16x4 __attribute__((ext_vector_type(4)));
typedef u16 u16x8 __attribute__((ext_vector_type(8)));
typedef u32 u32x4 __attribute__((ext_vector_type(4)));
typedef __bf16 bf16x8 __attribute__((ext_vector_type(8)));
typedef float f32x4 __attribute__((ext_vector_type(4)));

// global_load_lds: each lane writes 16B to (wave-uniform LDS base) + lane*16
#define GLL16(g, l) __builtin_amdgcn_global_load_lds( \
    (const __attribute__((address_space(1))) void*)(g), \
    (__attribute__((address_space(3))) void*)(l), 16, 0, 0)

// 0.125 (1/sqrt(64)) * log2(e): bake softmax base-2 conversion into the Q projection
#define QSCALE 0.18033688011112042f

__device__ __forceinline__ u16 f2bf(float f) {
  u32 u = __builtin_bit_cast(u32, f);
  u += 0x7fffu + ((u >> 16) & 1u);
  return (u16)(u >> 16);
}
__device__ __forceinline__ bf16x8 asbf(u16x8 v) { return __builtin_bit_cast(bf16x8, v); }

// ---------------- converts ----------------
__global__ void k_cvt_x(const float* __restrict__ x, u16* __restrict__ o) {
  int i = blockIdx.x * 256 + threadIdx.x;            // over n/4 = 1048576
  f32x4 v = ((const f32x4*)x)[i];
  u16x4 r = { f2bf(v[0]), f2bf(v[1]), f2bf(v[2]), f2bf(v[3]) };
  ((u16x4*)o)[i] = r;
}

// W [1024][1024] fp32 row-major -> W^T [1024][1024] bf16 (scaled)
__global__ void k_cvt_wT(const float* __restrict__ w, u16* __restrict__ wt, float scale) {
  __shared__ float t[32][33];
  int k0 = blockIdx.x << 5, n0 = blockIdx.y << 5;
  int lx = threadIdx.x & 31, ly = threadIdx.x >> 5;  // 32 x 8
  #pragma unroll
  for (int i = 0; i < 4; ++i)
    t[ly + 8*i][lx] = w[(size_t)(k0 + ly + 8*i) * 1024 + n0 + lx];
  __syncthreads();
  #pragma unroll
  for (int i = 0; i < 4; ++i)
    wt[(size_t)(n0 + ly + 8*i) * 1024 + k0 + lx] = f2bf(t[lx][ly + 8*i] * scale);
}

__global__ void k_bias(const float* __restrict__ bq, const float* __restrict__ bk,
                       const float* __restrict__ bv, float* __restrict__ o) {
  int i = blockIdx.x * 256 + threadIdx.x;            // 3072
  float v;
  if (i < 1024) v = bq[i] * QSCALE;
  else if (i < 2048) v = bk[i - 1024];
  else v = bv[i - 2048];
  o[i] = v;
}

// mask [2048][2048] int32 -> bit-packed [2048][64] u32 (bit k%32 of word k/32)
__global__ void k_maskbits(const int* __restrict__ mask, u32* __restrict__ bits) {
  int w = blockIdx.x * 256 + threadIdx.x;            // 131072 words
  const int* src = mask + (size_t)w * 32;
  u32 b = 0;
  #pragma unroll
  for (int i = 0; i < 32; ++i) b |= (src[i] != 0 ? 1u : 0u) << i;
  bits[w] = b;
}

// V [bh][2048][64] -> V^T [bh][64][2048] (coalesced both sides via LDS tile)
__global__ __launch_bounds__(256) void k_vT(const u16* __restrict__ vws, u16* __restrict__ vtws) {
  __shared__ u16 t[64][72];                          // 72: rows stay 16B-aligned
  const int bh = blockIdx.x;                         // 32
  const int st = blockIdx.y;                         // 32 s-tiles of 64
  const int tid = threadIdx.x;
  {
    const int s = tid >> 2, c4 = (tid & 3) << 4;
    const u16* src = vws + ((size_t)bh * 2048 + st * 64 + s) * 64 + c4;
    *(u16x8*)&t[s][c4] = *(const u16x8*)src;
    *(u16x8*)&t[s][c4 + 8] = *(const u16x8*)(src + 8);
  }
  __syncthreads();
  {
    const int d = tid >> 2, s0 = (tid & 3) << 4;
    u16 tmp[16];
    #pragma unroll
    for (int j = 0; j < 16; ++j) tmp[j] = t[s0 + j][d];
    u16* dst = vtws + ((size_t)bh * 64 + d) * 2048 + st * 64 + s0;
    *(u16x8*)dst = *(u16x8*)&tmp[0];
    *(u16x8*)(dst + 8) = *(u16x8*)&tmp[8];
  }
}

// ---------------- GEMM: C[M][N] = A[M][K=1024] * Bt[N][K]^T + bias ----------------
// EPI=0: N=3072, scatter to Q/K/V [bh][2048][64] (bf16, all natural layout)
// EPI=1: N=1024, write fp32 out [4096][1024]
template<int EPI>
__global__ __launch_bounds__(256)
void k_gemm(const u16* __restrict__ A, const u16* __restrict__ Bt,
            const float* __restrict__ bias, float* __restrict__ outF,
            u16* __restrict__ qws, u16* __restrict__ kws, u16* __restrict__ vws)
{
  __shared__ u16 As[128 * 32];
  __shared__ u16 Bs[128 * 32];
  const int tid = threadIdx.x;
  const int lane = tid & 63;
  const int wv = tid >> 6;
  const int g = lane >> 4, cc = lane & 15;
  const int wr = wv >> 1, wc = wv & 1;
  const int bm = blockIdx.y, bn = blockIdx.x;

  f32x4 acc[4][4] = {};

  for (int k0 = 0; k0 < 1024; k0 += 32) {
    __syncthreads();
    #pragma unroll
    for (int call = 0; call < 2; ++call) {
      int idx = call * 256 + tid;
      int row = idx >> 2;                       // tile row (64B rows, 4 x 16B slots)
      int sw = ((idx & 3) << 4) ^ ((row & 3) << 4);
      GLL16((const char*)(A + (size_t)(bm * 128 + row) * 1024 + k0) + sw,
            (char*)As + (call * 256 + wv * 64) * 16);
      GLL16((const char*)(Bt + (size_t)(bn * 128 + row) * 1024 + k0) + sw,
            (char*)Bs + (call * 256 + wv * 64) * 16);
    }
    __syncthreads();

    u16x8 a[4], b[4];
    #pragma unroll
    for (int m = 0; m < 4; ++m) {
      int row = wr * 64 + m * 16 + cc;
      a[m] = *(const u16x8*)((const char*)As + row * 64 + ((g * 16) ^ ((row & 3) << 4)));
    }
    #pragma unroll
    for (int n = 0; n < 4; ++n) {
      int row = wc * 64 + n * 16 + cc;
      b[n] = *(const u16x8*)((const char*)Bs + row * 64 + ((g * 16) ^ ((row & 3) << 4)));
    }
    #pragma unroll
    for (int m = 0; m < 4; ++m)
      #pragma unroll
      for (int n = 0; n < 4; ++n)
        acc[m][n] = __builtin_amdgcn_mfma_f32_16x16x32_bf16(asbf(a[m]), asbf(b[n]), acc[m][n], 0, 0, 0);
  }

  if constexpr (EPI == 1) {
    #pragma unroll
    for (int m = 0; m < 4; ++m) {
      int Mrow0 = bm * 128 + wr * 64 + m * 16 + g * 4;
      #pragma unroll
      for (int n = 0; n < 4; ++n) {
        int Ncol = bn * 128 + wc * 64 + n * 16 + cc;
        float bvv = bias[Ncol];
        #pragma unroll
        for (int r = 0; r < 4; ++r)
          outF[(size_t)(Mrow0 + r) * 1024 + Ncol] = acc[m][n][r] + bvv;
      }
    }
  } else {
    #pragma unroll
    for (int n = 0; n < 4; ++n) {
      int Ncol = bn * 128 + wc * 64 + n * 16 + cc;
      float bvv = bias[Ncol];
      int which = Ncol >> 10;
      int h = (Ncol >> 6) & 15;
      int d = Ncol & 63;
      u16* bp = which == 0 ? qws : (which == 1 ? kws : vws);
      #pragma unroll
      for (int m = 0; m < 4; ++m) {
        int Mrow0 = bm * 128 + wr * 64 + m * 16 + g * 4;
        int bb = Mrow0 >> 11;
        int s0 = Mrow0 & 2047;
        u16* dst = bp + ((size_t)(bb * 16 + h) * 2048 + s0) * 64 + d;
        #pragma unroll
        for (int r = 0; r < 4; ++r) dst[(size_t)r * 64] = f2bf(acc[m][n][r] + bvv);
      }
    }
  }
}

// ---------------- flash attention (swapped QK^T, static-max, 32 q-rows/wave) ----------------
// block = (bh, 128 q-rows); 4 waves x 32 q-rows (two 16-q halves A/B per wave);
// KV tiles of 64, double-buffered LDS. K staged PERMUTED (slot p <- key
// (p&32)+8*((p>>2)&3)+4*((p>>4)&1)+(p&3)) so the QK^T C-layout IS the PV A-fragment
// layout; P never leaves registers. K/V ds_reads and staging are shared by both
// q-halves (2x amortization of per-tile fixed cost).
__global__ __launch_bounds__(256, 4)
void k_attn(const u16* __restrict__ qws, const u16* __restrict__ kws,
            const u16* __restrict__ vtws, const u32* __restrict__ mbits,
            u16* __restrict__ ctx)
{
  __shared__ u16 Kt[2][64 * 64];   // [key-slot][d], 128B rows, XOR-swizzled
  __shared__ u16 Vt[2][64 * 64];   // [d][key],     128B rows, XOR-swizzled

  const int tid = threadIdx.x;
  const int lane = tid & 63;
  const int wv = tid >> 6;
  const int g = lane >> 4;
  const int cc = lane & 15;
  const int blk = blockIdx.x;
  const int qc = blk & 15;            // 16 chunks of 128 q-rows
  const int bh = blk >> 4;            // [0,32)
  const int b = bh >> 4, h = bh & 15;
  const size_t base = (size_t)bh * (2048 * 64);
  const int qrow = qc * 128 + wv * 32;   // wave's 32 q-rows

  // Q fragments, halves A (q=qrow+cc) and B (q=qrow+16+cc); k-dim d = 8g+j (+32)
  u16x8 qfA0, qfA1, qfB0, qfB1;
  {
    const u16* qpA = qws + base + (size_t)(qrow + cc) * 64 + g * 8;
    qfA0 = *(const u16x8*)qpA;
    qfA1 = *(const u16x8*)(qpA + 32);
    const u16* qpB = qpA + 16 * 64;
    qfB0 = *(const u16x8*)qpB;
    qfB1 = *(const u16x8*)(qpB + 32);
  }
  const u32* mqA = mbits + (size_t)(qrow + cc) * 64;
  const u32* mqB = mqA + 16 * 64;

  f32x4 oaccA[4] = {}, oaccB[4] = {};
  float lrunA = 0.f, lrunB = 0.f;

  auto STAGE = [&](int bufi, int kb) {
    #pragma unroll
    for (int call = 0; call < 2; ++call) {
      int idx = call * 256 + tid;
      int row = idx >> 3;                      // LDS row (128B, 8 x 16B slots)
      int sw = ((idx & 7) << 4) ^ ((row & 7) << 4);
      // permuted K source row: k(p) = (p&32) + 8*((p>>2)&3) + 4*((p>>4)&1) + (p&3)
      int krow = (row & 32) + (((row >> 2) & 3) << 3) + (((row >> 4) & 1) << 2) + (row & 3);
      GLL16((const char*)(kws + base + (size_t)(kb + krow) * 64) + sw,
            (char*)&Kt[bufi][0] + (call * 256 + wv * 64) * 16);
      GLL16((const char*)(vtws + base + (size_t)row * 2048 + kb) + sw,
            (char*)&Vt[bufi][0] + (call * 256 + wv * 64) * 16);
    }
  };

  STAGE(0, 0);
  __syncthreads();

  int cur = 0;
  for (int kb = 0; kb < 2048; kb += 64) {
    if (kb + 64 < 2048) STAGE(cur ^ 1, kb + 64);   // prefetch next tile

    // mask bits: lane's q-row (per half), 64 keys of this tile
    uint2 mwA = *(const uint2*)(mqA + (kb >> 5));
    uint2 mwB = *(const uint2*)(mqB + (kb >> 5));
    u32 mA0 = mwA.x >> (g * 8), mA1 = mwA.y >> (g * 8);
    u32 mB0 = mwB.x >> (g * 8), mB1 = mwB.y >> (g * 8);

    // QK^T (swapped): sc[t] lane layout q=cc, key-slot 16t+4g+r; kf shared by halves
    f32x4 scA[4], scB[4];
    #pragma unroll
    for (int t = 0; t < 4; ++t) {
      int row = t * 16 + cc;
      int swz = (row & 7) << 4;
      const char* kr = (const char*)&Kt[cur][0] + row * 128;
      u16x8 kf0 = *(const u16x8*)(kr + ((g * 16) ^ swz));
      u16x8 kf1 = *(const u16x8*)(kr + ((g * 16 + 64) ^ swz));
      f32x4 sA = {}, sB = {};
      sA = __builtin_amdgcn_mfma_f32_16x16x32_bf16(asbf(kf0), asbf(qfA0), sA, 0, 0, 0);
      sA = __builtin_amdgcn_mfma_f32_16x16x32_bf16(asbf(kf1), asbf(qfA1), sA, 0, 0, 0);
      sB = __builtin_amdgcn_mfma_f32_16x16x32_bf16(asbf(kf0), asbf(qfB0), sB, 0, 0, 0);
      sB = __builtin_amdgcn_mfma_f32_16x16x32_bf16(asbf(kf1), asbf(qfB1), sB, 0, 0, 0);
      scA[t] = sA;
      scB[t] = sB;
    }

    // softmax (static max): p = exp2(s); mask via sign-extended bit AND; sum.
    // sc[t][r] has key kb + 32*(t>>1) + 8g + 4*(t&1) + r
    u32 pkA[8], pkB[8];
    float rsA = 0.f, rsB = 0.f;
    #pragma unroll
    for (int t = 0; t < 4; ++t) {
      u32 mselA = (t >> 1) ? mA1 : mA0;
      u32 mselB = (t >> 1) ? mB1 : mB0;
      #pragma unroll
      for (int r = 0; r < 4; ++r) {
        int sh = 4 * (t & 1) + r;
        float pA = exp2f(scA[t][r]);
        float pB = exp2f(scB[t][r]);
        u32 mmA = (u32)__builtin_amdgcn_sbfe((int)mselA, sh, 1);  // 0 or -1
        u32 mmB = (u32)__builtin_amdgcn_sbfe((int)mselB, sh, 1);
        pA = __builtin_bit_cast(float, __builtin_bit_cast(u32, pA) & mmA);
        pB = __builtin_bit_cast(float, __builtin_bit_cast(u32, pB) & mmB);
        scA[t][r] = pA; rsA += pA;
        scB[t][r] = pB; rsB += pB;
      }
      u32 w0, w1;
      asm("v_cvt_pk_bf16_f32 %0, %1, %2" : "=v"(w0) : "v"(scA[t][0]), "v"(scA[t][1]));
      asm("v_cvt_pk_bf16_f32 %0, %1, %2" : "=v"(w1) : "v"(scA[t][2]), "v"(scA[t][3]));
      pkA[2 * t] = w0; pkA[2 * t + 1] = w1;
      asm("v_cvt_pk_bf16_f32 %0, %1, %2" : "=v"(w0) : "v"(scB[t][0]), "v"(scB[t][1]));
      asm("v_cvt_pk_bf16_f32 %0, %1, %2" : "=v"(w1) : "v"(scB[t][2]), "v"(scB[t][3]));
      pkB[2 * t] = w0; pkB[2 * t + 1] = w1;
    }
    rsA += __shfl_xor(rsA, 16);
    rsA += __shfl_xor(rsA, 32);
    rsB += __shfl_xor(rsB, 16);
    rsB += __shfl_xor(rsB, 32);
    lrunA += rsA;
    lrunB += rsB;

    // PV: O += P * V ; vf shared by halves
    #pragma unroll
    for (int ch = 0; ch < 2; ++ch) {
      u32x4 pwA = { pkA[4 * ch], pkA[4 * ch + 1], pkA[4 * ch + 2], pkA[4 * ch + 3] };
      u32x4 pwB = { pkB[4 * ch], pkB[4 * ch + 1], pkB[4 * ch + 2], pkB[4 * ch + 3] };
      u16x8 paA = __builtin_bit_cast(u16x8, pwA);
      u16x8 paB = __builtin_bit_cast(u16x8, pwB);
      #pragma unroll
      for (int f = 0; f < 4; ++f) {
        int row = f * 16 + cc;
        int swz = (row & 7) << 4;
        u16x8 vf = *(const u16x8*)((const char*)&Vt[cur][0] + row * 128 + ((g * 16 + ch * 64) ^ swz));
        oaccA[f] = __builtin_amdgcn_mfma_f32_16x16x32_bf16(asbf(paA), asbf(vf), oaccA[f], 0, 0, 0);
        oaccB[f] = __builtin_amdgcn_mfma_f32_16x16x32_bf16(asbf(paB), asbf(vf), oaccB[f], 0, 0, 0);
      }
    }

    __syncthreads();   // drains vmcnt (prefetch done) + LDS reads finished
    cur ^= 1;
  }

  // epilogue: output layout q = half*16 + 4g + r, d = 16f + cc
  float invA = 1.0f / lrunA, invB = 1.0f / lrunB;
  float iA[4], iB[4];
  #pragma unroll
  for (int r = 0; r < 4; ++r) {
    iA[r] = __shfl(invA, 4 * g + r);
    iB[r] = __shfl(invB, 4 * g + r);
  }
  #pragma unroll
  for (int f = 0; f < 4; ++f)
    #pragma unroll
    for (int r = 0; r < 4; ++r) {
      int qA = qrow + 4 * g + r;
      ctx[((size_t)(b * 2048 + qA)) * 1024 + h * 64 + f * 16 + cc] = f2bf(oaccA[f][r] * iA[r]);
      ctx[((size_t)(b * 2048 + qA + 16)) * 1024 + h * 64 + f * 16 + cc] = f2bf(oaccB[f][r] * iB[r]);
    }
}

// ---------------- launch ----------------
extern "C" void kernel_launch(void* const* d_in, const int* in_sizes, int n_in,
                              void* d_out, int out_size, void* d_ws, size_t ws_size,
                              hipStream_t stream) {
  (void)in_sizes; (void)n_in; (void)out_size; (void)ws_size;
  const float* x   = (const float*)d_in[0];
  const int*  mask = (const int*)d_in[1];
  const float* Wq  = (const float*)d_in[2];
  const float* bq  = (const float*)d_in[3];
  const float* Wk  = (const float*)d_in[4];
  const float* bk  = (const float*)d_in[5];
  const float* Wv  = (const float*)d_in[6];
  const float* bv  = (const float*)d_in[7];
  const float* Wo  = (const float*)d_in[8];
  const float* bo  = (const float*)d_in[9];

  char* p = (char*)d_ws;
  size_t off = 0;
  auto carve = [&](size_t n) { char* r = p + off; off = (off + n + 255) & ~(size_t)255; return r; };
  u16*  xb    = (u16*)carve((size_t)4096 * 1024 * 2);
  u16*  wqkvt = (u16*)carve((size_t)3072 * 1024 * 2);
  u16*  wot   = (u16*)carve((size_t)1024 * 1024 * 2);
  float* bqkv = (float*)carve(3072 * 4);
  u32*  mbits = (u32*)carve((size_t)2048 * 64 * 4);
  u16*  qws   = (u16*)carve((size_t)32 * 2048 * 64 * 2);
  u16*  kws   = (u16*)carve((size_t)32 * 2048 * 64 * 2);
  u16*  vws   = (u16*)carve((size_t)32 * 2048 * 64 * 2);
  u16*  vtws  = (u16*)carve((size_t)32 * 2048 * 64 * 2);
  u16*  ctx   = (u16*)carve((size_t)4096 * 1024 * 2);

  k_cvt_x<<<dim3(4096), dim3(256), 0, stream>>>(x, xb);
  k_cvt_wT<<<dim3(32, 32), dim3(256), 0, stream>>>(Wq, wqkvt, QSCALE);
  k_cvt_wT<<<dim3(32, 32), dim3(256), 0, stream>>>(Wk, wqkvt + 1024 * 1024, 1.0f);
  k_cvt_wT<<<dim3(32, 32), dim3(256), 0, stream>>>(Wv, wqkvt + 2 * 1024 * 1024, 1.0f);
  k_cvt_wT<<<dim3(32, 32), dim3(256), 0, stream>>>(Wo, wot, 1.0f);
  k_bias<<<dim3(12), dim3(256), 0, stream>>>(bq, bk, bv, bqkv);
  k_maskbits<<<dim3(512), dim3(256), 0, stream>>>(mask, mbits);

  k_gemm<0><<<dim3(24, 32), dim3(256), 0, stream>>>(xb, wqkvt, bqkv, nullptr, qws, kws, vws);
  k_vT<<<dim3(32, 32), dim3(256), 0, stream>>>(vws, vtws);
  k_attn<<<dim3(512), dim3(256), 0, stream>>>(qws, kws, vtws, mbits, ctx);
  k_gemm<1><<<dim3(8, 32), dim3(256), 0, stream>>>(ctx, wot, bo, (float*)d_out, nullptr, nullptr, nullptr);
}